// Round 1
// baseline (397.863 us; speedup 1.0000x reference)
//
#include <hip/hip_runtime.h>

#define N_NODES 20000
#define IN_FEAT 128
#define CONV_OUT 32
#define N_EDGES 640000
#define FC1_OUT 128

// ---------------- workspace layout (floats) ----------------
// agg   : [0        , 640000)   zeroed
// deg   : [640000   , 660000)   zeroed
// h3pre : [660000   , 660128)   zeroed
// dinv  : [660128   , 680128)
// h     : [680128   , 1320128)
// flat  : [1320128  , 1960128)

__global__ __launch_bounds__(256) void k_deg(const int* __restrict__ ei, float* __restrict__ deg) {
    int e = blockIdx.x * 256 + threadIdx.x;
    if (e < N_EDGES) {
        int d = ei[N_EDGES + e];
        if ((unsigned)d < N_NODES) atomicAdd(&deg[d], 1.0f);
    }
}

__global__ __launch_bounds__(256) void k_dinv(const float* __restrict__ deg, float* __restrict__ dinv) {
    int n = blockIdx.x * 256 + threadIdx.x;
    if (n < N_NODES) dinv[n] = rsqrtf(deg[n] + 1.0f);  // +1 for self-loop
}

// h[n][c] = sum_k x[n][k] * w[k][c]   (x:[N,128], w:[128,32])
__global__ __launch_bounds__(256) void k_gemm1(const float* __restrict__ x,
                                               const float* __restrict__ w,
                                               float* __restrict__ h) {
    __shared__ float xs[64][132];          // +4 pad: row stride 132 -> bank shift 4/row
    __shared__ float ws[128][32];
    int tid = threadIdx.x;
    int n0 = blockIdx.x * 64;

    // stage w (4096 f32 = 1024 f4)
    const float4* w4 = (const float4*)w;
    float4* ws4 = (float4*)ws;
    #pragma unroll
    for (int i = 0; i < 4; ++i) ws4[i * 256 + tid] = w4[i * 256 + tid];

    // stage x tile (64x128 = 2048 f4), padded rows
    const float4* x4 = (const float4*)x;
    #pragma unroll
    for (int i = 0; i < 8; ++i) {
        int idx = i * 256 + tid;           // f4 index in tile
        int nl  = idx >> 5;                // row (32 f4/row)
        int k4  = idx & 31;
        int n   = n0 + nl;
        float4 v = make_float4(0.f, 0.f, 0.f, 0.f);
        if (n < N_NODES) v = x4[(size_t)n * 32 + k4];
        *(float4*)&xs[nl][k4 * 4] = v;
    }
    __syncthreads();

    int c4  = tid & 7;                     // output f4-column 0..7
    int nl0 = tid >> 3;                    // 0..31
    const float4* wsrow = (const float4*)ws;   // [128][8]
    #pragma unroll
    for (int p = 0; p < 2; ++p) {
        int nl = nl0 + p * 32;
        float4 acc = make_float4(0.f, 0.f, 0.f, 0.f);
        #pragma unroll 8
        for (int k = 0; k < 128; k += 4) {
            float4 xv  = *(const float4*)&xs[nl][k];
            float4 wv0 = wsrow[(k + 0) * 8 + c4];
            float4 wv1 = wsrow[(k + 1) * 8 + c4];
            float4 wv2 = wsrow[(k + 2) * 8 + c4];
            float4 wv3 = wsrow[(k + 3) * 8 + c4];
            acc.x += xv.x * wv0.x + xv.y * wv1.x + xv.z * wv2.x + xv.w * wv3.x;
            acc.y += xv.x * wv0.y + xv.y * wv1.y + xv.z * wv2.y + xv.w * wv3.y;
            acc.z += xv.x * wv0.z + xv.y * wv1.z + xv.z * wv2.z + xv.w * wv3.z;
            acc.w += xv.x * wv0.w + xv.y * wv1.w + xv.z * wv2.w + xv.w * wv3.w;
        }
        int n = n0 + nl;
        if (n < N_NODES) *(float4*)&h[(size_t)n * 32 + c4 * 4] = acc;
    }
}

// agg[dst] += h[src] * dinv[src]*dinv[dst], one thread per (edge, f4)
__global__ __launch_bounds__(256) void k_scatter(const int* __restrict__ ei,
                                                 const float* __restrict__ h,
                                                 const float* __restrict__ dinv,
                                                 float* __restrict__ agg) {
    int idx = blockIdx.x * 256 + threadIdx.x;   // over N_EDGES*8
    if (idx >= N_EDGES * 8) return;
    int e  = idx >> 3;
    int f4 = idx & 7;
    int s = ei[e];
    int d = ei[N_EDGES + e];
    if ((unsigned)s >= N_NODES || (unsigned)d >= N_NODES) return;
    float norm = dinv[s] * dinv[d];
    float4 hv = *(const float4*)&h[(size_t)s * 32 + f4 * 4];
    float* ap = &agg[(size_t)d * 32 + f4 * 4];
    atomicAdd(ap + 0, hv.x * norm);
    atomicAdd(ap + 1, hv.y * norm);
    atomicAdd(ap + 2, hv.z * norm);
    atomicAdd(ap + 3, hv.w * norm);
}

// flat = relu(agg + h*dinv^2 (self loop) + b_conv)
__global__ __launch_bounds__(256) void k_flat(const float* __restrict__ agg,
                                              const float* __restrict__ h,
                                              const float* __restrict__ dinv,
                                              const float* __restrict__ bc,
                                              float* __restrict__ flat) {
    int idx = blockIdx.x * 256 + threadIdx.x;   // f4 index over 160000
    if (idx >= N_NODES * 8) return;
    int n = idx >> 3;
    float d2 = dinv[n] * dinv[n];
    float4 a  = ((const float4*)agg)[idx];
    float4 hv = ((const float4*)h)[idx];
    float4 b  = ((const float4*)bc)[idx & 7];
    float4 r;
    r.x = fmaxf(a.x + hv.x * d2 + b.x, 0.f);
    r.y = fmaxf(a.y + hv.y * d2 + b.y, 0.f);
    r.z = fmaxf(a.z + hv.z * d2 + b.z, 0.f);
    r.w = fmaxf(a.w + hv.w * d2 + b.w, 0.f);
    ((float4*)flat)[idx] = r;
}

// h3pre[j] += partial dot(flat, w_fc1[j]) ; grid = 25 chunks x 128 j
__global__ __launch_bounds__(256) void k_fc1(const float* __restrict__ flat,
                                             const float* __restrict__ w,
                                             float* __restrict__ h3pre) {
    int bid = blockIdx.x;
    int j  = bid & 127;
    int ch = bid >> 7;          // 0..24
    const float4* w4 = (const float4*)(w + (size_t)j * (CONV_OUT * N_NODES));
    const float4* f4 = (const float4*)flat;
    int base = ch * 6400;       // f4 units; 6400*25 = 160000
    float acc = 0.f;
    #pragma unroll 5
    for (int it = 0; it < 25; ++it) {
        int k = base + it * 256 + threadIdx.x;
        float4 wv = w4[k];
        float4 fv = f4[k];
        acc += wv.x * fv.x + wv.y * fv.y + wv.z * fv.z + wv.w * fv.w;
    }
    // wave reduce (64 lanes)
    #pragma unroll
    for (int o = 32; o > 0; o >>= 1) acc += __shfl_down(acc, o);
    __shared__ float red[4];
    if ((threadIdx.x & 63) == 0) red[threadIdx.x >> 6] = acc;
    __syncthreads();
    if (threadIdx.x == 0) atomicAdd(&h3pre[j], red[0] + red[1] + red[2] + red[3]);
}

// out[i] = relu(b2[i] + sum_j relu(h3pre[j]+b1[j]) * w2[i][j])
__global__ __launch_bounds__(256) void k_fc2(const float* __restrict__ h3pre,
                                             const float* __restrict__ b1,
                                             const float* __restrict__ w2,
                                             const float* __restrict__ b2,
                                             float* __restrict__ out) {
    __shared__ float4 h3s[32];
    int tid = threadIdx.x;
    if (tid < 32) {
        float4 v;
        v.x = fmaxf(h3pre[tid * 4 + 0] + b1[tid * 4 + 0], 0.f);
        v.y = fmaxf(h3pre[tid * 4 + 1] + b1[tid * 4 + 1], 0.f);
        v.z = fmaxf(h3pre[tid * 4 + 2] + b1[tid * 4 + 2], 0.f);
        v.w = fmaxf(h3pre[tid * 4 + 3] + b1[tid * 4 + 3], 0.f);
        h3s[tid] = v;
    }
    __syncthreads();
    int i = blockIdx.x * 256 + tid;
    if (i < N_NODES) {
        const float4* wr = (const float4*)(w2 + (size_t)i * FC1_OUT);
        float acc = b2[i];
        #pragma unroll
        for (int j = 0; j < 32; ++j) {
            float4 wv = wr[j];
            float4 hv = h3s[j];
            acc += wv.x * hv.x + wv.y * hv.y + wv.z * hv.z + wv.w * hv.w;
        }
        out[i] = fmaxf(acc, 0.f);
    }
}

extern "C" void kernel_launch(void* const* d_in, const int* in_sizes, int n_in,
                              void* d_out, int out_size, void* d_ws, size_t ws_size,
                              hipStream_t stream) {
    const float* x      = (const float*)d_in[0];
    const int*   ei     = (const int*)d_in[1];
    const float* w_conv = (const float*)d_in[2];
    const float* b_conv = (const float*)d_in[3];
    const float* w_fc1  = (const float*)d_in[4];
    const float* b_fc1  = (const float*)d_in[5];
    const float* w_fc2  = (const float*)d_in[6];
    const float* b_fc2  = (const float*)d_in[7];
    float* ws    = (float*)d_ws;
    float* agg   = ws;
    float* deg   = ws + 640000;
    float* h3pre = ws + 660000;
    float* dinv  = ws + 660128;
    float* h     = ws + 680128;
    float* flat  = ws + 1320128;
    float* out   = (float*)d_out;

    hipMemsetAsync(d_ws, 0, 660128 * sizeof(float), stream);
    k_deg<<<(N_EDGES + 255) / 256, 256, 0, stream>>>(ei, deg);
    k_dinv<<<(N_NODES + 255) / 256, 256, 0, stream>>>(deg, dinv);
    k_gemm1<<<(N_NODES + 63) / 64, 256, 0, stream>>>(x, w_conv, h);
    k_scatter<<<(N_EDGES * 8) / 256, 256, 0, stream>>>(ei, h, dinv, agg);
    k_flat<<<(N_NODES * 8 + 255) / 256, 256, 0, stream>>>(agg, h, dinv, b_conv, flat);
    k_fc1<<<128 * 25, 256, 0, stream>>>(flat, w_fc1, h3pre);
    k_fc2<<<(N_NODES + 255) / 256, 256, 0, stream>>>(h3pre, b_fc1, w_fc2, b_fc2, out);
}

// Round 2
// 219.490 us; speedup vs baseline: 1.8127x; 1.8127x over previous
//
#include <hip/hip_runtime.h>

#define N_NODES 20000
#define IN_FEAT 128
#define CONV_OUT 32
#define N_EDGES 640000
#define FC1_OUT 128

// ---------------- workspace layout (4-byte units) ----------------
// startv (int) [0       , 20000)   deg counts -> row start offsets (zeroed)
// cursor (int) [20000   , 40000)   fill cursor; after fill == row end
// h3pre  (f32) [40000   , 40128)   zeroed
// dinv   (f32) [40128   , 60128)
// csr    (int) [60128   , 700128)  src ids grouped by dst
// h      (f32) [700128  , 1340128) x@w_conv, pre-scaled by dinv[n]
// flat   (f32) [1340128 , 1980128)

__global__ __launch_bounds__(256) void k_degi(const int* __restrict__ ei, int* __restrict__ cnt) {
    int e = blockIdx.x * 256 + threadIdx.x;
    if (e < N_EDGES) {
        int s = ei[e];
        int d = ei[N_EDGES + e];
        if ((unsigned)s < N_NODES && (unsigned)d < N_NODES) atomicAdd(&cnt[d], 1);
    }
}

#define SCAN_CHUNK 20
__global__ __launch_bounds__(1024) void k_scan(int* __restrict__ cnt /* -> start */,
                                               int* __restrict__ cursor,
                                               float* __restrict__ dinv) {
    __shared__ int ps[1024];
    int t = threadIdx.x;
    int base = t * SCAN_CHUNK;
    int local[SCAN_CHUNK];
    int sum = 0;
    #pragma unroll
    for (int i = 0; i < SCAN_CHUNK; ++i) {
        int n = base + i;
        int v = (n < N_NODES) ? cnt[n] : 0;
        local[i] = v;
        sum += v;
    }
    ps[t] = sum;
    __syncthreads();
    #pragma unroll
    for (int off = 1; off < 1024; off <<= 1) {
        int v = (t >= off) ? ps[t - off] : 0;
        __syncthreads();
        ps[t] += v;
        __syncthreads();
    }
    int run = (t == 0) ? 0 : ps[t - 1];
    #pragma unroll
    for (int i = 0; i < SCAN_CHUNK; ++i) {
        int n = base + i;
        if (n < N_NODES) {
            cnt[n] = run;                        // row start (overwrites count)
            cursor[n] = run;
            dinv[n] = rsqrtf((float)local[i] + 1.0f);  // +1 self-loop
            run += local[i];
        }
    }
}

// h[n][c] = dinv[n] * sum_k x[n][k]*w[k][c]
__global__ __launch_bounds__(256) void k_gemm1(const float* __restrict__ x,
                                               const float* __restrict__ w,
                                               const float* __restrict__ dinv,
                                               float* __restrict__ h) {
    __shared__ float xs[64][132];
    __shared__ float ws[128][32];
    int tid = threadIdx.x;
    int n0 = blockIdx.x * 64;

    const float4* w4 = (const float4*)w;
    float4* ws4 = (float4*)ws;
    #pragma unroll
    for (int i = 0; i < 4; ++i) ws4[i * 256 + tid] = w4[i * 256 + tid];

    const float4* x4 = (const float4*)x;
    #pragma unroll
    for (int i = 0; i < 8; ++i) {
        int idx = i * 256 + tid;
        int nl  = idx >> 5;
        int k4  = idx & 31;
        int n   = n0 + nl;
        float4 v = make_float4(0.f, 0.f, 0.f, 0.f);
        if (n < N_NODES) v = x4[(size_t)n * 32 + k4];
        *(float4*)&xs[nl][k4 * 4] = v;
    }
    __syncthreads();

    int c4  = tid & 7;
    int nl0 = tid >> 3;
    const float4* wsrow = (const float4*)ws;
    #pragma unroll
    for (int p = 0; p < 2; ++p) {
        int nl = nl0 + p * 32;
        float4 acc = make_float4(0.f, 0.f, 0.f, 0.f);
        #pragma unroll 8
        for (int k = 0; k < 128; k += 4) {
            float4 xv  = *(const float4*)&xs[nl][k];
            float4 wv0 = wsrow[(k + 0) * 8 + c4];
            float4 wv1 = wsrow[(k + 1) * 8 + c4];
            float4 wv2 = wsrow[(k + 2) * 8 + c4];
            float4 wv3 = wsrow[(k + 3) * 8 + c4];
            acc.x += xv.x * wv0.x + xv.y * wv1.x + xv.z * wv2.x + xv.w * wv3.x;
            acc.y += xv.x * wv0.y + xv.y * wv1.y + xv.z * wv2.y + xv.w * wv3.y;
            acc.z += xv.x * wv0.z + xv.y * wv1.z + xv.z * wv2.z + xv.w * wv3.z;
            acc.w += xv.x * wv0.w + xv.y * wv1.w + xv.z * wv2.w + xv.w * wv3.w;
        }
        int n = n0 + nl;
        if (n < N_NODES) {
            float dv = dinv[n];
            acc.x *= dv; acc.y *= dv; acc.z *= dv; acc.w *= dv;
            *(float4*)&h[(size_t)n * 32 + c4 * 4] = acc;
        }
    }
}

__global__ __launch_bounds__(256) void k_fill(const int* __restrict__ ei,
                                              int* __restrict__ cursor,
                                              int* __restrict__ csr) {
    int e = blockIdx.x * 256 + threadIdx.x;
    if (e < N_EDGES) {
        int s = ei[e];
        int d = ei[N_EDGES + e];
        if ((unsigned)s < N_NODES && (unsigned)d < N_NODES) {
            int pos = atomicAdd(&cursor[d], 1);
            csr[pos] = s;
        }
    }
}

// flat[n] = relu(dinv[n] * (hs[n] + sum_{src in in(n)} hs[src]) + b)
// 8 lanes per node, each owns one float4 of the 32 features.
__global__ __launch_bounds__(256) void k_gather(const int* __restrict__ startv,
                                                const int* __restrict__ endv,
                                                const int* __restrict__ csr,
                                                const float* __restrict__ h,
                                                const float* __restrict__ dinv,
                                                const float* __restrict__ bc,
                                                float* __restrict__ flat) {
    int tid = threadIdx.x;
    int n  = blockIdx.x * 32 + (tid >> 3);
    int f4 = tid & 7;
    if (n >= N_NODES) return;
    const float4* h4 = (const float4*)h;
    float4 acc = h4[(size_t)n * 8 + f4];          // self-loop (pre-scaled)
    int p0 = startv[n], p1 = endv[n];
    for (int p = p0; p < p1; ++p) {
        int s = csr[p];
        float4 v = h4[(size_t)s * 8 + f4];
        acc.x += v.x; acc.y += v.y; acc.z += v.z; acc.w += v.w;
    }
    float dv = dinv[n];
    float4 b = ((const float4*)bc)[f4];
    float4 r;
    r.x = fmaxf(acc.x * dv + b.x, 0.f);
    r.y = fmaxf(acc.y * dv + b.y, 0.f);
    r.z = fmaxf(acc.z * dv + b.z, 0.f);
    r.w = fmaxf(acc.w * dv + b.w, 0.f);
    ((float4*)flat)[(size_t)n * 8 + f4] = r;
}

__global__ __launch_bounds__(256) void k_fc1(const float* __restrict__ flat,
                                             const float* __restrict__ w,
                                             float* __restrict__ h3pre) {
    int bid = blockIdx.x;
    int j  = bid & 127;
    int ch = bid >> 7;
    const float4* w4 = (const float4*)(w + (size_t)j * (CONV_OUT * N_NODES));
    const float4* f4 = (const float4*)flat;
    int base = ch * 6400;
    float acc = 0.f;
    #pragma unroll 5
    for (int it = 0; it < 25; ++it) {
        int k = base + it * 256 + threadIdx.x;
        float4 wv = w4[k];
        float4 fv = f4[k];
        acc += wv.x * fv.x + wv.y * fv.y + wv.z * fv.z + wv.w * fv.w;
    }
    #pragma unroll
    for (int o = 32; o > 0; o >>= 1) acc += __shfl_down(acc, o);
    __shared__ float red[4];
    if ((threadIdx.x & 63) == 0) red[threadIdx.x >> 6] = acc;
    __syncthreads();
    if (threadIdx.x == 0) atomicAdd(&h3pre[j], red[0] + red[1] + red[2] + red[3]);
}

__global__ __launch_bounds__(256) void k_fc2(const float* __restrict__ h3pre,
                                             const float* __restrict__ b1,
                                             const float* __restrict__ w2,
                                             const float* __restrict__ b2,
                                             float* __restrict__ out) {
    __shared__ float4 h3s[32];
    int tid = threadIdx.x;
    if (tid < 32) {
        float4 v;
        v.x = fmaxf(h3pre[tid * 4 + 0] + b1[tid * 4 + 0], 0.f);
        v.y = fmaxf(h3pre[tid * 4 + 1] + b1[tid * 4 + 1], 0.f);
        v.z = fmaxf(h3pre[tid * 4 + 2] + b1[tid * 4 + 2], 0.f);
        v.w = fmaxf(h3pre[tid * 4 + 3] + b1[tid * 4 + 3], 0.f);
        h3s[tid] = v;
    }
    __syncthreads();
    int i = blockIdx.x * 256 + tid;
    if (i < N_NODES) {
        const float4* wr = (const float4*)(w2 + (size_t)i * FC1_OUT);
        float acc = b2[i];
        #pragma unroll
        for (int j = 0; j < 32; ++j) {
            float4 wv = wr[j];
            float4 hv = h3s[j];
            acc += wv.x * hv.x + wv.y * hv.y + wv.z * hv.z + wv.w * hv.w;
        }
        out[i] = fmaxf(acc, 0.f);
    }
}

extern "C" void kernel_launch(void* const* d_in, const int* in_sizes, int n_in,
                              void* d_out, int out_size, void* d_ws, size_t ws_size,
                              hipStream_t stream) {
    const float* x      = (const float*)d_in[0];
    const int*   ei     = (const int*)d_in[1];
    const float* w_conv = (const float*)d_in[2];
    const float* b_conv = (const float*)d_in[3];
    const float* w_fc1  = (const float*)d_in[4];
    const float* b_fc1  = (const float*)d_in[5];
    const float* w_fc2  = (const float*)d_in[6];
    const float* b_fc2  = (const float*)d_in[7];
    float* ws = (float*)d_ws;
    int*   startv = (int*)ws;               // [0, 20000)
    int*   cursor = (int*)(ws + 20000);     // [20000, 40000)
    float* h3pre  = ws + 40000;             // [40000, 40128)
    float* dinv   = ws + 40128;             // [40128, 60128)
    int*   csr    = (int*)(ws + 60128);     // [60128, 700128)
    float* h      = ws + 700128;            // [700128, 1340128)
    float* flat   = ws + 1340128;           // [1340128, 1980128)
    float* out    = (float*)d_out;

    hipMemsetAsync(d_ws, 0, 40128 * sizeof(float), stream);  // startv+cursor+h3pre
    k_degi<<<(N_EDGES + 255) / 256, 256, 0, stream>>>(ei, startv);
    k_scan<<<1, 1024, 0, stream>>>(startv, cursor, dinv);
    k_gemm1<<<(N_NODES + 63) / 64, 256, 0, stream>>>(x, w_conv, dinv, h);
    k_fill<<<(N_EDGES + 255) / 256, 256, 0, stream>>>(ei, cursor, csr);
    k_gather<<<(N_NODES + 31) / 32, 256, 0, stream>>>(startv, cursor, csr, h, dinv, b_conv, flat);
    k_fc1<<<128 * 25, 256, 0, stream>>>(flat, w_fc1, h3pre);
    k_fc2<<<(N_NODES + 255) / 256, 256, 0, stream>>>(h3pre, b_fc1, w_fc2, b_fc2, out);
}

// Round 3
// 219.388 us; speedup vs baseline: 1.8135x; 1.0005x over previous
//
#include <hip/hip_runtime.h>

#define N_NODES 20000
#define IN_FEAT 128
#define CONV_OUT 32
#define N_EDGES 640000
#define FC1_OUT 128

// ---------------- workspace layout (4-byte units) ----------------
// startv (int) [0       , 20000)   deg counts -> row start offsets (zeroed)
// cursor (int) [20000   , 40000)   fill cursor; after fill == row end
// h3pre  (f32) [40000   , 40128)   zeroed
// dinv   (f32) [40128   , 60128)
// csr    (int) [60128   , 700128)  src ids grouped by dst
// h      (f32) [700128  , 1340128) x@w_conv, pre-scaled by dinv[n]
// flat   (f32) [1340128 , 1980128)

#define ZERO_WORDS 40128   // startv + cursor + h3pre (divisible by 4)

__global__ __launch_bounds__(256) void k_zero(float4* __restrict__ p) {
    int i = blockIdx.x * 256 + threadIdx.x;
    if (i < ZERO_WORDS / 4) p[i] = make_float4(0.f, 0.f, 0.f, 0.f);
}

__global__ __launch_bounds__(256) void k_degi(const int* __restrict__ ei, int* __restrict__ cnt) {
    int e = blockIdx.x * 256 + threadIdx.x;
    if (e < N_EDGES) {
        int s = ei[e];
        int d = ei[N_EDGES + e];
        if ((unsigned)s < N_NODES && (unsigned)d < N_NODES) atomicAdd(&cnt[d], 1);
    }
}

#define SCAN_CHUNK 20
__global__ __launch_bounds__(1024) void k_scan(int* __restrict__ cnt /* -> start */,
                                               int* __restrict__ cursor,
                                               float* __restrict__ dinv) {
    __shared__ int ps[1024];
    int t = threadIdx.x;
    int base = t * SCAN_CHUNK;
    int local[SCAN_CHUNK];
    int sum = 0;
    #pragma unroll
    for (int i = 0; i < SCAN_CHUNK; ++i) {
        int n = base + i;
        int v = (n < N_NODES) ? cnt[n] : 0;
        local[i] = v;
        sum += v;
    }
    ps[t] = sum;
    __syncthreads();
    #pragma unroll
    for (int off = 1; off < 1024; off <<= 1) {
        int v = (t >= off) ? ps[t - off] : 0;
        __syncthreads();
        ps[t] += v;
        __syncthreads();
    }
    int run = (t == 0) ? 0 : ps[t - 1];
    #pragma unroll
    for (int i = 0; i < SCAN_CHUNK; ++i) {
        int n = base + i;
        if (n < N_NODES) {
            cnt[n] = run;                        // row start (overwrites count)
            cursor[n] = run;
            dinv[n] = rsqrtf((float)local[i] + 1.0f);  // +1 self-loop
            run += local[i];
        }
    }
}

// h[n][c] = dinv[n] * sum_k x[n][k]*w[k][c]
__global__ __launch_bounds__(256) void k_gemm1(const float* __restrict__ x,
                                               const float* __restrict__ w,
                                               const float* __restrict__ dinv,
                                               float* __restrict__ h) {
    __shared__ float xs[64][132];
    __shared__ float ws[128][32];
    int tid = threadIdx.x;
    int n0 = blockIdx.x * 64;

    const float4* w4 = (const float4*)w;
    float4* ws4 = (float4*)ws;
    #pragma unroll
    for (int i = 0; i < 4; ++i) ws4[i * 256 + tid] = w4[i * 256 + tid];

    const float4* x4 = (const float4*)x;
    #pragma unroll
    for (int i = 0; i < 8; ++i) {
        int idx = i * 256 + tid;
        int nl  = idx >> 5;
        int k4  = idx & 31;
        int n   = n0 + nl;
        float4 v = make_float4(0.f, 0.f, 0.f, 0.f);
        if (n < N_NODES) v = x4[(size_t)n * 32 + k4];
        *(float4*)&xs[nl][k4 * 4] = v;
    }
    __syncthreads();

    int c4  = tid & 7;
    int nl0 = tid >> 3;
    const float4* wsrow = (const float4*)ws;
    #pragma unroll
    for (int p = 0; p < 2; ++p) {
        int nl = nl0 + p * 32;
        float4 acc = make_float4(0.f, 0.f, 0.f, 0.f);
        #pragma unroll 8
        for (int k = 0; k < 128; k += 4) {
            float4 xv  = *(const float4*)&xs[nl][k];
            float4 wv0 = wsrow[(k + 0) * 8 + c4];
            float4 wv1 = wsrow[(k + 1) * 8 + c4];
            float4 wv2 = wsrow[(k + 2) * 8 + c4];
            float4 wv3 = wsrow[(k + 3) * 8 + c4];
            acc.x += xv.x * wv0.x + xv.y * wv1.x + xv.z * wv2.x + xv.w * wv3.x;
            acc.y += xv.x * wv0.y + xv.y * wv1.y + xv.z * wv2.y + xv.w * wv3.y;
            acc.z += xv.x * wv0.z + xv.y * wv1.z + xv.z * wv2.z + xv.w * wv3.z;
            acc.w += xv.x * wv0.w + xv.y * wv1.w + xv.z * wv2.w + xv.w * wv3.w;
        }
        int n = n0 + nl;
        if (n < N_NODES) {
            float dv = dinv[n];
            acc.x *= dv; acc.y *= dv; acc.z *= dv; acc.w *= dv;
            *(float4*)&h[(size_t)n * 32 + c4 * 4] = acc;
        }
    }
}

__global__ __launch_bounds__(256) void k_fill(const int* __restrict__ ei,
                                              int* __restrict__ cursor,
                                              int* __restrict__ csr) {
    int e = blockIdx.x * 256 + threadIdx.x;
    if (e < N_EDGES) {
        int s = ei[e];
        int d = ei[N_EDGES + e];
        if ((unsigned)s < N_NODES && (unsigned)d < N_NODES) {
            int pos = atomicAdd(&cursor[d], 1);
            csr[pos] = s;
        }
    }
}

// flat[n] = relu(dinv[n] * (hs[n] + sum_{src in in(n)} hs[src]) + b)
__global__ __launch_bounds__(256) void k_gather(const int* __restrict__ startv,
                                                const int* __restrict__ endv,
                                                const int* __restrict__ csr,
                                                const float* __restrict__ h,
                                                const float* __restrict__ dinv,
                                                const float* __restrict__ bc,
                                                float* __restrict__ flat) {
    int tid = threadIdx.x;
    int n  = blockIdx.x * 32 + (tid >> 3);
    int f4 = tid & 7;
    if (n >= N_NODES) return;
    const float4* h4 = (const float4*)h;
    float4 acc = h4[(size_t)n * 8 + f4];          // self-loop (pre-scaled)
    int p0 = startv[n], p1 = endv[n];
    for (int p = p0; p < p1; ++p) {
        int s = csr[p];
        float4 v = h4[(size_t)s * 8 + f4];
        acc.x += v.x; acc.y += v.y; acc.z += v.z; acc.w += v.w;
    }
    float dv = dinv[n];
    float4 b = ((const float4*)bc)[f4];
    float4 r;
    r.x = fmaxf(acc.x * dv + b.x, 0.f);
    r.y = fmaxf(acc.y * dv + b.y, 0.f);
    r.z = fmaxf(acc.z * dv + b.z, 0.f);
    r.w = fmaxf(acc.w * dv + b.w, 0.f);
    ((float4*)flat)[(size_t)n * 8 + f4] = r;
}

__global__ __launch_bounds__(256) void k_fc1(const float* __restrict__ flat,
                                             const float* __restrict__ w,
                                             float* __restrict__ h3pre) {
    int bid = blockIdx.x;
    int j  = bid & 127;
    int ch = bid >> 7;
    const float4* w4 = (const float4*)(w + (size_t)j * (CONV_OUT * N_NODES));
    const float4* f4 = (const float4*)flat;
    int base = ch * 6400;
    float acc = 0.f;
    #pragma unroll 5
    for (int it = 0; it < 25; ++it) {
        int k = base + it * 256 + threadIdx.x;
        float4 wv = w4[k];
        float4 fv = f4[k];
        acc += wv.x * fv.x + wv.y * fv.y + wv.z * fv.z + wv.w * fv.w;
    }
    #pragma unroll
    for (int o = 32; o > 0; o >>= 1) acc += __shfl_down(acc, o);
    __shared__ float red[4];
    if ((threadIdx.x & 63) == 0) red[threadIdx.x >> 6] = acc;
    __syncthreads();
    if (threadIdx.x == 0) atomicAdd(&h3pre[j], red[0] + red[1] + red[2] + red[3]);
}

__global__ __launch_bounds__(256) void k_fc2(const float* __restrict__ h3pre,
                                             const float* __restrict__ b1,
                                             const float* __restrict__ w2,
                                             const float* __restrict__ b2,
                                             float* __restrict__ out) {
    __shared__ float4 h3s[32];
    int tid = threadIdx.x;
    if (tid < 32) {
        float4 v;
        v.x = fmaxf(h3pre[tid * 4 + 0] + b1[tid * 4 + 0], 0.f);
        v.y = fmaxf(h3pre[tid * 4 + 1] + b1[tid * 4 + 1], 0.f);
        v.z = fmaxf(h3pre[tid * 4 + 2] + b1[tid * 4 + 2], 0.f);
        v.w = fmaxf(h3pre[tid * 4 + 3] + b1[tid * 4 + 3], 0.f);
        h3s[tid] = v;
    }
    __syncthreads();
    int i = blockIdx.x * 256 + tid;
    if (i < N_NODES) {
        const float4* wr = (const float4*)(w2 + (size_t)i * FC1_OUT);
        float acc = b2[i];
        #pragma unroll
        for (int j = 0; j < 32; ++j) {
            float4 wv = wr[j];
            float4 hv = h3s[j];
            acc += wv.x * hv.x + wv.y * hv.y + wv.z * hv.z + wv.w * hv.w;
        }
        out[i] = fmaxf(acc, 0.f);
    }
}

extern "C" void kernel_launch(void* const* d_in, const int* in_sizes, int n_in,
                              void* d_out, int out_size, void* d_ws, size_t ws_size,
                              hipStream_t stream) {
    const float* x      = (const float*)d_in[0];
    const int*   ei     = (const int*)d_in[1];
    const float* w_conv = (const float*)d_in[2];
    const float* b_conv = (const float*)d_in[3];
    const float* w_fc1  = (const float*)d_in[4];
    const float* b_fc1  = (const float*)d_in[5];
    const float* w_fc2  = (const float*)d_in[6];
    const float* b_fc2  = (const float*)d_in[7];
    float* ws = (float*)d_ws;
    int*   startv = (int*)ws;               // [0, 20000)
    int*   cursor = (int*)(ws + 20000);     // [20000, 40000)
    float* h3pre  = ws + 40000;             // [40000, 40128)
    float* dinv   = ws + 40128;             // [40128, 60128)
    int*   csr    = (int*)(ws + 60128);     // [60128, 700128)
    float* h      = ws + 700128;            // [700128, 1340128)
    float* flat   = ws + 1340128;           // [1340128, 1980128)
    float* out    = (float*)d_out;

    k_zero<<<(ZERO_WORDS / 4 + 255) / 256, 256, 0, stream>>>((float4*)d_ws);
    k_degi<<<(N_EDGES + 255) / 256, 256, 0, stream>>>(ei, startv);
    k_scan<<<1, 1024, 0, stream>>>(startv, cursor, dinv);
    k_gemm1<<<(N_NODES + 63) / 64, 256, 0, stream>>>(x, w_conv, dinv, h);
    k_fill<<<(N_EDGES + 255) / 256, 256, 0, stream>>>(ei, cursor, csr);
    k_gather<<<(N_NODES + 31) / 32, 256, 0, stream>>>(startv, cursor, csr, h, dinv, b_conv, flat);
    k_fc1<<<128 * 25, 256, 0, stream>>>(flat, w_fc1, h3pre);
    k_fc2<<<(N_NODES + 255) / 256, 256, 0, stream>>>(h3pre, b_fc1, w_fc2, b_fc2, out);
}

// Round 4
// 203.267 us; speedup vs baseline: 1.9573x; 1.0793x over previous
//
#include <hip/hip_runtime.h>

#define N_NODES 20000
#define IN_FEAT 128
#define CONV_OUT 32
#define N_EDGES 640000
#define FC1_OUT 128

// ---------------- workspace layout (4-byte units) ----------------
// startv (int) [0       , 20000)   deg counts -> row start offsets (zeroed)
// cursor (int) [20000   , 40000)   fill cursor; after fill == row end
// h3pre  (f32) [40000   , 40128)   zeroed
// dinv   (f32) [40128   , 60128)
// csr    (int) [60128   , 700128)  src ids grouped by dst
// h      (f32) [700128  , 1340128) x@w_conv, pre-scaled by dinv[n]
// flat   (f32) [1340128 , 1980128)

#define ZERO_WORDS 40128   // startv + cursor + h3pre (divisible by 4)

__global__ __launch_bounds__(256) void k_zero(float4* __restrict__ p) {
    int i = blockIdx.x * 256 + threadIdx.x;
    if (i < ZERO_WORDS / 4) p[i] = make_float4(0.f, 0.f, 0.f, 0.f);
}

__global__ __launch_bounds__(256) void k_degi(const int* __restrict__ ei, int* __restrict__ cnt) {
    int e = blockIdx.x * 256 + threadIdx.x;
    if (e < N_EDGES) {
        int s = ei[e];
        int d = ei[N_EDGES + e];
        if ((unsigned)s < N_NODES && (unsigned)d < N_NODES) atomicAdd(&cnt[d], 1);
    }
}

#define SCAN_CHUNK 20
__global__ __launch_bounds__(1024) void k_scan(int* __restrict__ cnt /* -> start */,
                                               int* __restrict__ cursor,
                                               float* __restrict__ dinv) {
    __shared__ int ps[1024];
    int t = threadIdx.x;
    int base = t * SCAN_CHUNK;
    int local[SCAN_CHUNK];
    int sum = 0;
    #pragma unroll
    for (int i = 0; i < SCAN_CHUNK; ++i) {
        int n = base + i;
        int v = (n < N_NODES) ? cnt[n] : 0;
        local[i] = v;
        sum += v;
    }
    ps[t] = sum;
    __syncthreads();
    #pragma unroll
    for (int off = 1; off < 1024; off <<= 1) {
        int v = (t >= off) ? ps[t - off] : 0;
        __syncthreads();
        ps[t] += v;
        __syncthreads();
    }
    int run = (t == 0) ? 0 : ps[t - 1];
    #pragma unroll
    for (int i = 0; i < SCAN_CHUNK; ++i) {
        int n = base + i;
        if (n < N_NODES) {
            cnt[n] = run;                        // row start (overwrites count)
            cursor[n] = run;
            dinv[n] = rsqrtf((float)local[i] + 1.0f);  // +1 self-loop
            run += local[i];
        }
    }
}

// h[n][c] = dinv[n] * sum_k x[n][k]*w[k][c]
__global__ __launch_bounds__(256) void k_gemm1(const float* __restrict__ x,
                                               const float* __restrict__ w,
                                               const float* __restrict__ dinv,
                                               float* __restrict__ h) {
    __shared__ float xs[64][132];
    __shared__ float ws[128][32];
    int tid = threadIdx.x;
    int n0 = blockIdx.x * 64;

    const float4* w4 = (const float4*)w;
    float4* ws4 = (float4*)ws;
    #pragma unroll
    for (int i = 0; i < 4; ++i) ws4[i * 256 + tid] = w4[i * 256 + tid];

    const float4* x4 = (const float4*)x;
    #pragma unroll
    for (int i = 0; i < 8; ++i) {
        int idx = i * 256 + tid;
        int nl  = idx >> 5;
        int k4  = idx & 31;
        int n   = n0 + nl;
        float4 v = make_float4(0.f, 0.f, 0.f, 0.f);
        if (n < N_NODES) v = x4[(size_t)n * 32 + k4];
        *(float4*)&xs[nl][k4 * 4] = v;
    }
    __syncthreads();

    int c4  = tid & 7;
    int nl0 = tid >> 3;
    const float4* wsrow = (const float4*)ws;
    #pragma unroll
    for (int p = 0; p < 2; ++p) {
        int nl = nl0 + p * 32;
        float4 acc = make_float4(0.f, 0.f, 0.f, 0.f);
        #pragma unroll 8
        for (int k = 0; k < 128; k += 4) {
            float4 xv  = *(const float4*)&xs[nl][k];
            float4 wv0 = wsrow[(k + 0) * 8 + c4];
            float4 wv1 = wsrow[(k + 1) * 8 + c4];
            float4 wv2 = wsrow[(k + 2) * 8 + c4];
            float4 wv3 = wsrow[(k + 3) * 8 + c4];
            acc.x += xv.x * wv0.x + xv.y * wv1.x + xv.z * wv2.x + xv.w * wv3.x;
            acc.y += xv.x * wv0.y + xv.y * wv1.y + xv.z * wv2.y + xv.w * wv3.y;
            acc.z += xv.x * wv0.z + xv.y * wv1.z + xv.z * wv2.z + xv.w * wv3.z;
            acc.w += xv.x * wv0.w + xv.y * wv1.w + xv.z * wv2.w + xv.w * wv3.w;
        }
        int n = n0 + nl;
        if (n < N_NODES) {
            float dv = dinv[n];
            acc.x *= dv; acc.y *= dv; acc.z *= dv; acc.w *= dv;
            *(float4*)&h[(size_t)n * 32 + c4 * 4] = acc;
        }
    }
}

__global__ __launch_bounds__(256) void k_fill(const int* __restrict__ ei,
                                              int* __restrict__ cursor,
                                              int* __restrict__ csr) {
    int e = blockIdx.x * 256 + threadIdx.x;
    if (e < N_EDGES) {
        int s = ei[e];
        int d = ei[N_EDGES + e];
        if ((unsigned)s < N_NODES && (unsigned)d < N_NODES) {
            int pos = atomicAdd(&cursor[d], 1);
            csr[pos] = s;
        }
    }
}

// Wave-per-node gather: 64 lanes = 8 edge-slots x 8 f4-features.
// flat[n] = relu(dinv[n] * (hs[n] + sum_{src in in(n)} hs[src]) + b)
__global__ __launch_bounds__(256) void k_gather(const int* __restrict__ startv,
                                                const int* __restrict__ endv,
                                                const int* __restrict__ csr,
                                                const float* __restrict__ h,
                                                const float* __restrict__ dinv,
                                                const float* __restrict__ bc,
                                                float* __restrict__ flat) {
    int tid  = threadIdx.x;
    int lane = tid & 63;
    int n    = blockIdx.x * 4 + (tid >> 6);
    if (n >= N_NODES) return;
    int es = lane >> 3;     // edge slot 0..7
    int f4 = lane & 7;      // feature float4 0..7
    const float4* h4 = (const float4*)h;
    float4 acc = make_float4(0.f, 0.f, 0.f, 0.f);
    int p0 = startv[n], p1 = endv[n];
    #pragma unroll 2
    for (int p = p0 + es; p < p1; p += 8) {
        int s = csr[p];
        float4 v = h4[(size_t)s * 8 + f4];
        acc.x += v.x; acc.y += v.y; acc.z += v.z; acc.w += v.w;
    }
    // reduce over edge slots (lane bits 3,4,5)
    #pragma unroll
    for (int m = 8; m < 64; m <<= 1) {
        acc.x += __shfl_xor(acc.x, m);
        acc.y += __shfl_xor(acc.y, m);
        acc.z += __shfl_xor(acc.z, m);
        acc.w += __shfl_xor(acc.w, m);
    }
    if (lane < 8) {
        float4 self = h4[(size_t)n * 8 + f4];   // pre-scaled self-loop
        float dv = dinv[n];
        float4 b = ((const float4*)bc)[f4];
        float4 r;
        r.x = fmaxf((acc.x + self.x) * dv + b.x, 0.f);
        r.y = fmaxf((acc.y + self.y) * dv + b.y, 0.f);
        r.z = fmaxf((acc.z + self.z) * dv + b.z, 0.f);
        r.w = fmaxf((acc.w + self.w) * dv + b.w, 0.f);
        ((float4*)flat)[(size_t)n * 8 + f4] = r;
    }
}

__global__ __launch_bounds__(256) void k_fc1(const float* __restrict__ flat,
                                             const float* __restrict__ w,
                                             float* __restrict__ h3pre) {
    int bid = blockIdx.x;
    int j  = bid & 127;
    int ch = bid >> 7;
    const float4* w4 = (const float4*)(w + (size_t)j * (CONV_OUT * N_NODES));
    const float4* f4 = (const float4*)flat;
    int base = ch * 6400;
    float acc = 0.f;
    #pragma unroll 5
    for (int it = 0; it < 25; ++it) {
        int k = base + it * 256 + threadIdx.x;
        float4 wv = w4[k];
        float4 fv = f4[k];
        acc += wv.x * fv.x + wv.y * fv.y + wv.z * fv.z + wv.w * fv.w;
    }
    #pragma unroll
    for (int o = 32; o > 0; o >>= 1) acc += __shfl_down(acc, o);
    __shared__ float red[4];
    if ((threadIdx.x & 63) == 0) red[threadIdx.x >> 6] = acc;
    __syncthreads();
    if (threadIdx.x == 0) atomicAdd(&h3pre[j], red[0] + red[1] + red[2] + red[3]);
}

__global__ __launch_bounds__(256) void k_fc2(const float* __restrict__ h3pre,
                                             const float* __restrict__ b1,
                                             const float* __restrict__ w2,
                                             const float* __restrict__ b2,
                                             float* __restrict__ out) {
    __shared__ float4 h3s[32];
    int tid = threadIdx.x;
    if (tid < 32) {
        float4 v;
        v.x = fmaxf(h3pre[tid * 4 + 0] + b1[tid * 4 + 0], 0.f);
        v.y = fmaxf(h3pre[tid * 4 + 1] + b1[tid * 4 + 1], 0.f);
        v.z = fmaxf(h3pre[tid * 4 + 2] + b1[tid * 4 + 2], 0.f);
        v.w = fmaxf(h3pre[tid * 4 + 3] + b1[tid * 4 + 3], 0.f);
        h3s[tid] = v;
    }
    __syncthreads();
    int i = blockIdx.x * 256 + tid;
    if (i < N_NODES) {
        const float4* wr = (const float4*)(w2 + (size_t)i * FC1_OUT);
        float acc = b2[i];
        #pragma unroll
        for (int j = 0; j < 32; ++j) {
            float4 wv = wr[j];
            float4 hv = h3s[j];
            acc += wv.x * hv.x + wv.y * hv.y + wv.z * hv.z + wv.w * hv.w;
        }
        out[i] = fmaxf(acc, 0.f);
    }
}

extern "C" void kernel_launch(void* const* d_in, const int* in_sizes, int n_in,
                              void* d_out, int out_size, void* d_ws, size_t ws_size,
                              hipStream_t stream) {
    const float* x      = (const float*)d_in[0];
    const int*   ei     = (const int*)d_in[1];
    const float* w_conv = (const float*)d_in[2];
    const float* b_conv = (const float*)d_in[3];
    const float* w_fc1  = (const float*)d_in[4];
    const float* b_fc1  = (const float*)d_in[5];
    const float* w_fc2  = (const float*)d_in[6];
    const float* b_fc2  = (const float*)d_in[7];
    float* ws = (float*)d_ws;
    int*   startv = (int*)ws;               // [0, 20000)
    int*   cursor = (int*)(ws + 20000);     // [20000, 40000)
    float* h3pre  = ws + 40000;             // [40000, 40128)
    float* dinv   = ws + 40128;             // [40128, 60128)
    int*   csr    = (int*)(ws + 60128);     // [60128, 700128)
    float* h      = ws + 700128;            // [700128, 1340128)
    float* flat   = ws + 1340128;           // [1340128, 1980128)
    float* out    = (float*)d_out;

    k_zero<<<(ZERO_WORDS / 4 + 255) / 256, 256, 0, stream>>>((float4*)d_ws);
    k_degi<<<(N_EDGES + 255) / 256, 256, 0, stream>>>(ei, startv);
    k_scan<<<1, 1024, 0, stream>>>(startv, cursor, dinv);
    k_gemm1<<<(N_NODES + 63) / 64, 256, 0, stream>>>(x, w_conv, dinv, h);
    k_fill<<<(N_EDGES + 255) / 256, 256, 0, stream>>>(ei, cursor, csr);
    k_gather<<<(N_NODES + 3) / 4, 256, 0, stream>>>(startv, cursor, csr, h, dinv, b_conv, flat);
    k_fc1<<<128 * 25, 256, 0, stream>>>(flat, w_fc1, h3pre);
    k_fc2<<<(N_NODES + 255) / 256, 256, 0, stream>>>(h3pre, b_fc1, w_fc2, b_fc2, out);
}

// Round 5
// 164.891 us; speedup vs baseline: 2.4129x; 1.2327x over previous
//
#include <hip/hip_runtime.h>

#define N_NODES 20000
#define IN_FEAT 128
#define CONV_OUT 32
#define N_EDGES 640000
#define FC1_OUT 128

// ---------------- workspace layout (4-byte units) ----------------
// cnt    (int) [0       , 20000)    per-dst degree counts (zeroed)
// h3pre  (f32) [20000   , 20128)    zeroed
// startv (int) [20128   , 40132)    exclusive scan of cnt, 20001 entries
// dinv   (f32) [40132   , 60132)
// r      (int) [60132   , 700132)   per-edge slot within dst bucket
// csr    (int) [700132  , 1340132)  src ids grouped by dst
// h      (f32) [1340132 , 1980132)  x@w_conv, pre-scaled by dinv[n]
// flat   (f32) [1980132 , 2620132)

#define ZERO_WORDS 20128   // cnt + h3pre

__global__ __launch_bounds__(256) void k_zero(float4* __restrict__ p) {
    int i = blockIdx.x * 256 + threadIdx.x;
    if (i < ZERO_WORDS / 4) p[i] = make_float4(0.f, 0.f, 0.f, 0.f);
}

// count degree AND record each edge's slot within its dst bucket
__global__ __launch_bounds__(256) void k_degslot(const int* __restrict__ ei,
                                                 int* __restrict__ cnt,
                                                 int* __restrict__ r) {
    int e = blockIdx.x * 256 + threadIdx.x;
    if (e < N_EDGES) {
        int d = ei[N_EDGES + e];
        r[e] = atomicAdd(&cnt[d], 1);
    }
}

#define SCAN_T 1024
#define SCAN_CHUNK 20
__global__ __launch_bounds__(1024) void k_scan(const int* __restrict__ cnt,
                                               int* __restrict__ startv,
                                               float* __restrict__ dinv) {
    __shared__ int ld[SCAN_T * SCAN_CHUNK];   // 20480 ints = 80 KB
    __shared__ int ps[SCAN_T];
    int t = threadIdx.x;
    // coalesced int4 load cnt -> LDS (5000 int4, pad to 5120 with zeros)
    const int4* c4 = (const int4*)cnt;
    int4* l4 = (int4*)ld;
    #pragma unroll
    for (int i = 0; i < 5; ++i) {
        int idx = i * SCAN_T + t;
        l4[idx] = (idx < N_NODES / 4) ? c4[idx] : make_int4(0, 0, 0, 0);
    }
    __syncthreads();
    int local[SCAN_CHUNK];
    int base = t * SCAN_CHUNK;
    int sum = 0;
    #pragma unroll
    for (int i = 0; i < SCAN_CHUNK; ++i) { local[i] = ld[base + i]; sum += local[i]; }
    ps[t] = sum;
    __syncthreads();
    for (int off = 1; off < SCAN_T; off <<= 1) {
        int v = (t >= off) ? ps[t - off] : 0;
        __syncthreads();
        ps[t] += v;
        __syncthreads();
    }
    int run = (t == 0) ? 0 : ps[t - 1];
    #pragma unroll
    for (int i = 0; i < SCAN_CHUNK; ++i) {
        int n = base + i;
        ld[n] = run;                                   // exclusive start
        if (n < N_NODES) dinv[n] = rsqrtf((float)local[i] + 1.0f);  // +1 self-loop
        run += local[i];
    }
    __syncthreads();
    // coalesced int4 store LDS -> startv
    int4* s4 = (int4*)startv;
    #pragma unroll
    for (int i = 0; i < 5; ++i) {
        int idx = i * SCAN_T + t;
        if (idx < N_NODES / 4) s4[idx] = l4[idx];
    }
    if (t == 0) startv[N_NODES] = N_EDGES;
}

// h[n][c] = dinv[n] * sum_k x[n][k]*w[k][c]
__global__ __launch_bounds__(256) void k_gemm1(const float* __restrict__ x,
                                               const float* __restrict__ w,
                                               const float* __restrict__ dinv,
                                               float* __restrict__ h) {
    __shared__ float xs[64][132];
    __shared__ float ws[128][32];
    int tid = threadIdx.x;
    int n0 = blockIdx.x * 64;

    const float4* w4 = (const float4*)w;
    float4* ws4 = (float4*)ws;
    #pragma unroll
    for (int i = 0; i < 4; ++i) ws4[i * 256 + tid] = w4[i * 256 + tid];

    const float4* x4 = (const float4*)x;
    #pragma unroll
    for (int i = 0; i < 8; ++i) {
        int idx = i * 256 + tid;
        int nl  = idx >> 5;
        int k4  = idx & 31;
        int n   = n0 + nl;
        float4 v = make_float4(0.f, 0.f, 0.f, 0.f);
        if (n < N_NODES) v = x4[(size_t)n * 32 + k4];
        *(float4*)&xs[nl][k4 * 4] = v;
    }
    __syncthreads();

    int c4  = tid & 7;
    int nl0 = tid >> 3;
    const float4* wsrow = (const float4*)ws;
    #pragma unroll
    for (int p = 0; p < 2; ++p) {
        int nl = nl0 + p * 32;
        float4 acc = make_float4(0.f, 0.f, 0.f, 0.f);
        #pragma unroll 8
        for (int k = 0; k < 128; k += 4) {
            float4 xv  = *(const float4*)&xs[nl][k];
            float4 wv0 = wsrow[(k + 0) * 8 + c4];
            float4 wv1 = wsrow[(k + 1) * 8 + c4];
            float4 wv2 = wsrow[(k + 2) * 8 + c4];
            float4 wv3 = wsrow[(k + 3) * 8 + c4];
            acc.x += xv.x * wv0.x + xv.y * wv1.x + xv.z * wv2.x + xv.w * wv3.x;
            acc.y += xv.x * wv0.y + xv.y * wv1.y + xv.z * wv2.y + xv.w * wv3.y;
            acc.z += xv.x * wv0.z + xv.y * wv1.z + xv.z * wv2.z + xv.w * wv3.z;
            acc.w += xv.x * wv0.w + xv.y * wv1.w + xv.z * wv2.w + xv.w * wv3.w;
        }
        int n = n0 + nl;
        if (n < N_NODES) {
            float dv = dinv[n];
            acc.x *= dv; acc.y *= dv; acc.z *= dv; acc.w *= dv;
            *(float4*)&h[(size_t)n * 32 + c4 * 4] = acc;
        }
    }
}

// atomic-free CSR fill using precomputed slots
__global__ __launch_bounds__(256) void k_fill(const int* __restrict__ ei,
                                              const int* __restrict__ startv,
                                              const int* __restrict__ r,
                                              int* __restrict__ csr) {
    int e = blockIdx.x * 256 + threadIdx.x;
    if (e < N_EDGES) {
        int s = ei[e];
        int d = ei[N_EDGES + e];
        csr[startv[d] + r[e]] = s;
    }
}

// Wave-per-node gather: 64 lanes = 8 edge-slots x 8 f4-features.
// flat[n] = relu(dinv[n] * (hs[n] + sum_{src in in(n)} hs[src]) + b)
__global__ __launch_bounds__(256) void k_gather(const int* __restrict__ startv,
                                                const int* __restrict__ csr,
                                                const float* __restrict__ h,
                                                const float* __restrict__ dinv,
                                                const float* __restrict__ bc,
                                                float* __restrict__ flat) {
    int tid  = threadIdx.x;
    int lane = tid & 63;
    int n    = blockIdx.x * 4 + (tid >> 6);
    if (n >= N_NODES) return;
    int es = lane >> 3;     // edge slot 0..7
    int f4 = lane & 7;      // feature float4 0..7
    const float4* h4 = (const float4*)h;
    float4 acc = make_float4(0.f, 0.f, 0.f, 0.f);
    int p0 = startv[n], p1 = startv[n + 1];
    #pragma unroll 2
    for (int p = p0 + es; p < p1; p += 8) {
        int s = csr[p];
        float4 v = h4[(size_t)s * 8 + f4];
        acc.x += v.x; acc.y += v.y; acc.z += v.z; acc.w += v.w;
    }
    #pragma unroll
    for (int m = 8; m < 64; m <<= 1) {
        acc.x += __shfl_xor(acc.x, m);
        acc.y += __shfl_xor(acc.y, m);
        acc.z += __shfl_xor(acc.z, m);
        acc.w += __shfl_xor(acc.w, m);
    }
    if (lane < 8) {
        float4 self = h4[(size_t)n * 8 + f4];   // pre-scaled self-loop
        float dv = dinv[n];
        float4 b = ((const float4*)bc)[f4];
        float4 r_;
        r_.x = fmaxf((acc.x + self.x) * dv + b.x, 0.f);
        r_.y = fmaxf((acc.y + self.y) * dv + b.y, 0.f);
        r_.z = fmaxf((acc.z + self.z) * dv + b.z, 0.f);
        r_.w = fmaxf((acc.w + self.w) * dv + b.w, 0.f);
        ((float4*)flat)[(size_t)n * 8 + f4] = r_;
    }
}

__global__ __launch_bounds__(256) void k_fc1(const float* __restrict__ flat,
                                             const float* __restrict__ w,
                                             float* __restrict__ h3pre) {
    int bid = blockIdx.x;
    int j  = bid & 127;
    int ch = bid >> 7;
    const float4* w4 = (const float4*)(w + (size_t)j * (CONV_OUT * N_NODES));
    const float4* f4 = (const float4*)flat;
    int base = ch * 6400;
    float acc = 0.f;
    #pragma unroll 5
    for (int it = 0; it < 25; ++it) {
        int k = base + it * 256 + threadIdx.x;
        float4 wv = w4[k];
        float4 fv = f4[k];
        acc += wv.x * fv.x + wv.y * fv.y + wv.z * fv.z + wv.w * fv.w;
    }
    #pragma unroll
    for (int o = 32; o > 0; o >>= 1) acc += __shfl_down(acc, o);
    __shared__ float red[4];
    if ((threadIdx.x & 63) == 0) red[threadIdx.x >> 6] = acc;
    __syncthreads();
    if (threadIdx.x == 0) atomicAdd(&h3pre[j], red[0] + red[1] + red[2] + red[3]);
}

__global__ __launch_bounds__(256) void k_fc2(const float* __restrict__ h3pre,
                                             const float* __restrict__ b1,
                                             const float* __restrict__ w2,
                                             const float* __restrict__ b2,
                                             float* __restrict__ out) {
    __shared__ float4 h3s[32];
    int tid = threadIdx.x;
    if (tid < 32) {
        float4 v;
        v.x = fmaxf(h3pre[tid * 4 + 0] + b1[tid * 4 + 0], 0.f);
        v.y = fmaxf(h3pre[tid * 4 + 1] + b1[tid * 4 + 1], 0.f);
        v.z = fmaxf(h3pre[tid * 4 + 2] + b1[tid * 4 + 2], 0.f);
        v.w = fmaxf(h3pre[tid * 4 + 3] + b1[tid * 4 + 3], 0.f);
        h3s[tid] = v;
    }
    __syncthreads();
    int i = blockIdx.x * 256 + tid;
    if (i < N_NODES) {
        const float4* wr = (const float4*)(w2 + (size_t)i * FC1_OUT);
        float acc = b2[i];
        #pragma unroll
        for (int j = 0; j < 32; ++j) {
            float4 wv = wr[j];
            float4 hv = h3s[j];
            acc += wv.x * hv.x + wv.y * hv.y + wv.z * hv.z + wv.w * hv.w;
        }
        out[i] = fmaxf(acc, 0.f);
    }
}

extern "C" void kernel_launch(void* const* d_in, const int* in_sizes, int n_in,
                              void* d_out, int out_size, void* d_ws, size_t ws_size,
                              hipStream_t stream) {
    const float* x      = (const float*)d_in[0];
    const int*   ei     = (const int*)d_in[1];
    const float* w_conv = (const float*)d_in[2];
    const float* b_conv = (const float*)d_in[3];
    const float* w_fc1  = (const float*)d_in[4];
    const float* b_fc1  = (const float*)d_in[5];
    const float* w_fc2  = (const float*)d_in[6];
    const float* b_fc2  = (const float*)d_in[7];
    float* ws = (float*)d_ws;
    int*   cnt    = (int*)ws;               // [0, 20000)
    float* h3pre  = ws + 20000;             // [20000, 20128)
    int*   startv = (int*)(ws + 20128);     // [20128, 40132)  20001 entries
    float* dinv   = ws + 40132;             // [40132, 60132)
    int*   r      = (int*)(ws + 60132);     // [60132, 700132)
    int*   csr    = (int*)(ws + 700132);    // [700132, 1340132)
    float* h      = ws + 1340132;           // [1340132, 1980132)
    float* flat   = ws + 1980132;           // [1980132, 2620132)
    float* out    = (float*)d_out;

    k_zero<<<(ZERO_WORDS / 4 + 255) / 256, 256, 0, stream>>>((float4*)d_ws);
    k_degslot<<<(N_EDGES + 255) / 256, 256, 0, stream>>>(ei, cnt, r);
    k_scan<<<1, SCAN_T, 0, stream>>>(cnt, startv, dinv);
    k_gemm1<<<(N_NODES + 63) / 64, 256, 0, stream>>>(x, w_conv, dinv, h);
    k_fill<<<(N_EDGES + 255) / 256, 256, 0, stream>>>(ei, startv, r, csr);
    k_gather<<<(N_NODES + 3) / 4, 256, 0, stream>>>(startv, csr, h, dinv, b_conv, flat);
    k_fc1<<<128 * 25, 256, 0, stream>>>(flat, w_fc1, h3pre);
    k_fc2<<<(N_NODES + 255) / 256, 256, 0, stream>>>(h3pre, b_fc1, w_fc2, b_fc2, out);
}